// Round 1
// baseline (235.273 us; speedup 1.0000x reference)
//
#include <hip/hip_runtime.h>
#include <hip/hip_bf16.h>
#include <stdint.h>

// B=4, N=M=4096, C=1024, D=128. fp32 in/out, bf16 MFMA internally.
// out[n] = (sum_{m>n} e^{s[n,m]} v[m]) / (sum_all_m e^{s[n,m]})
// Fixed-frame softmax (s ~ N(0,1)) -> no running max; KV-split partials
// combine as plain (O, l) sums.
// attn: S^T via swapped MFMA operands; P C-layout -> PV B-layout via lane
// bpermute; K/V staged by global_load_lds (16B) with XOR swizzle on the
// GLOBAL gather side.
// Round 8: qkv_kernel rebuilt as 512-thread / 8-wave blocks (same 128x128
// tile, same 72KB double-buffered LDS). Occupancy 6 -> 12 waves/CU avg and
// per-thread staging halves (6 loads/ktile vs 12): qkv was latency-bound at
// 13% occupancy / 19% HBM, 4x above its ~15us memory floor.

typedef __attribute__((ext_vector_type(8))) __bf16    bf16x8;
typedef __attribute__((ext_vector_type(4))) float     floatx4;
typedef __attribute__((ext_vector_type(8))) uint16_t  u16x8;
typedef __attribute__((ext_vector_type(4))) uint32_t  u32x4;

#define DEVFN __device__ __forceinline__

DEVFN uint16_t f32_to_bf16(float f) {                 // round-to-nearest-even
  uint32_t u = __builtin_bit_cast(uint32_t, f);
  u += 0x7FFFu + ((u >> 16) & 1u);
  return (uint16_t)(u >> 16);
}

DEVFN uint32_t bcast(float f) { return __builtin_bit_cast(uint32_t, f); }

DEVFN uint32_t pack2_bf16(float a, float b) {         // round-half-up pair
  return ((bcast(a) + 0x8000u) >> 16) | ((bcast(b) + 0x8000u) & 0xFFFF0000u);
}

DEVFN u32x4 pack_bf16_8(float4 a0, float4 a1) {
  u32x4 o;
  o[0] = pack2_bf16(a0.x, a0.y);
  o[1] = pack2_bf16(a0.z, a0.w);
  o[2] = pack2_bf16(a1.x, a1.y);
  o[3] = pack2_bf16(a1.z, a1.w);
  return o;
}

DEVFN void gl2lds16(const void* g, void* l) {         // async 16B/lane -> LDS
  __builtin_amdgcn_global_load_lds(
      (const __attribute__((address_space(1))) void*)g,
      (__attribute__((address_space(3))) void*)l, 16, 0, 0);
}

// ---------------- Phase 0: W [1024,128] fp32 -> Wt [128,1024] bf16 (x3) ----
__global__ __launch_bounds__(256) void wt_kernel(
    const float* __restrict__ Wq, const float* __restrict__ Wk,
    const float* __restrict__ Wv, uint16_t* __restrict__ wt) {
  int tid = blockIdx.x * 256 + threadIdx.x;
  int mat = tid >> 14;
  int rem = tid & 16383;
  int n  = rem & 127;
  int k0 = rem >> 7;
  const float* W = (mat == 0) ? Wq : ((mat == 1) ? Wk : Wv);
  u16x8 v;
#pragma unroll
  for (int j = 0; j < 8; ++j) v[j] = f32_to_bf16(W[(k0 * 8 + j) * 128 + n]);
  *(u16x8*)&wt[mat * (128 * 1024) + n * 1024 + k0 * 8] = v;
}

// ---------------- Phase 1: fused QKV GEMM, 8-wave blocks -------------------
// 128x128 output tile, K=1024 in 16 double-buffered ktiles of 64.
// 8 waves arranged 4(row-groups of 32) x 2(col-groups of 64); each wave:
// acc[2][4] (32 VGPR), 12 ds_read_b128 + 16 MFMA per ktile.
__global__ __launch_bounds__(512, 4) void qkv_kernel(
    const float* __restrict__ x, const float* __restrict__ y,
    const uint16_t* __restrict__ wt, uint16_t* __restrict__ q,
    uint16_t* __restrict__ k, uint16_t* __restrict__ vt) {
  constexpr int LDT = 72;
  constexpr int ABUF = 128 * LDT;
  __shared__ __align__(16) uint16_t sA[2 * ABUF];
  __shared__ __align__(16) uint16_t sW[2 * ABUF];
  const int t = threadIdx.x;
  const int mat = blockIdx.y, rt = blockIdx.x;
  const float* A = (mat == 0) ? x : y;
  const uint16_t* Wt = wt + mat * (128 * 1024);
  const int lane = t & 63, wv = t >> 6;        // wv 0..7
  const int wr = wv >> 1, wc = wv & 1;         // 4 row-groups x 2 col-groups
  const int cidx = lane & 15, quad = lane >> 4;
  const int sr = t >> 3;                       // 0..63, +u*64 -> rows 0..127
  const int sc = (t & 7) * 8;                  // k-offset 0,8,..,56
  const int Arow0 = rt * 128;

  floatx4 acc[2][4];
#pragma unroll
  for (int rg = 0; rg < 2; ++rg)
#pragma unroll
    for (int ng = 0; ng < 4; ++ng) acc[rg][ng] = (floatx4){0.f, 0.f, 0.f, 0.f};

  float4 a0r[2], a1r[2];
  u16x8 wfr[2];
#pragma unroll
  for (int u = 0; u < 2; ++u) {
    int row = u * 64 + sr;
    const float* ap = &A[(size_t)(Arow0 + row) * 1024 + sc];
    a0r[u] = *(const float4*)ap;
    a1r[u] = *(const float4*)(ap + 4);
    wfr[u] = *(const u16x8*)&Wt[row * 1024 + sc];
  }
#pragma unroll
  for (int u = 0; u < 2; ++u) {
    int row = u * 64 + sr;
    *(u32x4*)&sA[row * LDT + sc] = pack_bf16_8(a0r[u], a1r[u]);
    *(u16x8*)&sW[row * LDT + sc] = wfr[u];
  }
  __syncthreads();

  for (int kt = 0; kt < 16; ++kt) {
    const int cur = kt & 1, nxt = cur ^ 1;
    if (kt < 15) {
      const int kc = (kt + 1) * 64;
#pragma unroll
      for (int u = 0; u < 2; ++u) {
        int row = u * 64 + sr;
        const float* ap = &A[(size_t)(Arow0 + row) * 1024 + kc + sc];
        a0r[u] = *(const float4*)ap;
        a1r[u] = *(const float4*)(ap + 4);
        wfr[u] = *(const u16x8*)&Wt[row * 1024 + kc + sc];
      }
    }
    bf16x8 af[2][2];
#pragma unroll
    for (int rg = 0; rg < 2; ++rg)
#pragma unroll
      for (int ks = 0; ks < 2; ++ks)
        af[rg][ks] = *(const bf16x8*)
            &sA[cur * ABUF + (wr * 32 + rg * 16 + cidx) * LDT + ks * 32 + quad * 8];
#pragma unroll
    for (int ng = 0; ng < 4; ++ng) {
      bf16x8 b0 = *(const bf16x8*)
          &sW[cur * ABUF + (wc * 64 + ng * 16 + cidx) * LDT + quad * 8];
      bf16x8 b1 = *(const bf16x8*)
          &sW[cur * ABUF + (wc * 64 + ng * 16 + cidx) * LDT + 32 + quad * 8];
#pragma unroll
      for (int rg = 0; rg < 2; ++rg) {
        acc[rg][ng] = __builtin_amdgcn_mfma_f32_16x16x32_bf16(af[rg][0], b0, acc[rg][ng], 0, 0, 0);
        acc[rg][ng] = __builtin_amdgcn_mfma_f32_16x16x32_bf16(af[rg][1], b1, acc[rg][ng], 0, 0, 0);
      }
    }
    if (kt < 15) {
#pragma unroll
      for (int u = 0; u < 2; ++u) {
        int row = u * 64 + sr;
        *(u32x4*)&sA[nxt * ABUF + row * LDT + sc] = pack_bf16_8(a0r[u], a1r[u]);
        *(u16x8*)&sW[nxt * ABUF + row * LDT + sc] = wfr[u];
      }
    }
    __syncthreads();
  }

  if (mat < 2) {
    uint16_t* outp = (mat == 0) ? q : k;
#pragma unroll
    for (int rg = 0; rg < 2; ++rg)
#pragma unroll
      for (int r = 0; r < 4; ++r) {
        int row = Arow0 + wr * 32 + rg * 16 + quad * 4 + r;
#pragma unroll
        for (int ng = 0; ng < 4; ++ng)
          outp[row * 128 + wc * 64 + ng * 16 + cidx] = f32_to_bf16(acc[rg][ng][r]);
      }
  } else {
    int bq = rt >> 5;
    int mbase = (rt & 31) * 128;
#pragma unroll
    for (int rg = 0; rg < 2; ++rg)
#pragma unroll
      for (int r = 0; r < 4; ++r) {
        int m = mbase + wr * 32 + rg * 16 + quad * 4 + r;
#pragma unroll
        for (int ng = 0; ng < 4; ++ng)
          vt[(size_t)(bq * 128 + wc * 64 + ng * 16 + cidx) * 4096 + m] =
              f32_to_bf16(acc[rg][ng][r]);
      }
  }
}

// ---------------- Phase 2: attention, 32 q-cols/wave, 2x fragment reuse ----
// grid (32 q-tiles, hcount kv-chunks, 4 batches), 256 thr = 4 waves x 32 q.
// K,V double-buffered unpadded LDS, XOR-swizzled via the global gather.
__global__ __launch_bounds__(256, 2) void attn_kernel(
    const uint16_t* __restrict__ q, const uint16_t* __restrict__ k,
    const uint16_t* __restrict__ vt, float* __restrict__ opart,
    float* __restrict__ lpart, int mlen, int iters) {
  constexpr int KB = 16384, VB = 16384;        // 64x128 / 128x64 u16, unpadded
  __shared__ __align__(16) uint8_t sK[2 * KB];
  __shared__ __align__(16) uint8_t sV[2 * VB];
  const int t = threadIdx.x;
  const int lane = t & 63, wv = t >> 6;
  const int cidx = lane & 15, quad = lane >> 4;
  const int qt = blockIdx.x, h = blockIdx.y, b = blockIdx.z;
  const int qmin = qt * 128 + wv * 32;         // lowest q row of this wave
  const int mbase = h * mlen;

  const uint16_t* qb = q + (size_t)(b * 4096) * 128;
  const uint8_t* kb = (const uint8_t*)(k + (size_t)(b * 4096) * 128);
  const uint8_t* vb = (const uint8_t*)(vt + (size_t)(b * 128) * 4096);

  const float SC = 0.12751744610657223f;  // log2(e)/sqrt(128), q unscaled

  // chunk-invariant swizzled gather offsets (see round-6 derivation)
  int kOffL[4], vOffL[4], kLds[4], vLds[4];
#pragma unroll
  for (int u = 0; u < 4; ++u) {
    int r  = wv * 16 + u * 4 + (lane >> 4);
    int g  = (lane & 15) ^ (r & 15);
    kOffL[u] = r * 256 + g * 16;
    kLds[u]  = (wv * 16 + u * 4) * 256;
    int rv = wv * 32 + u * 8 + (lane >> 3);
    int gv = (lane & 7) ^ (rv & 7);
    vOffL[u] = rv * 8192 + gv * 16;
    vLds[u]  = (wv * 32 + u * 8) * 128;
  }

  bf16x8 qf[2][4];   // B-frags: qg group col n = qmin+qg*16+cidx
#pragma unroll
  for (int qg = 0; qg < 2; ++qg)
#pragma unroll
    for (int ks = 0; ks < 4; ++ks)
      qf[qg][ks] = *(const bf16x8*)
          &qb[(qmin + qg * 16 + cidx) * 128 + ks * 32 + quad * 8];

  floatx4 O[2][8];   // out^T tiles: row d = dg*16+quad*4+r, col n per qg
#pragma unroll
  for (int qg = 0; qg < 2; ++qg)
#pragma unroll
    for (int dg = 0; dg < 8; ++dg) O[qg][dg] = (floatx4){0.f, 0.f, 0.f, 0.f};
  float lsum[2] = {0.f, 0.f};

  // stage chunk 0 into buffer 0
#pragma unroll
  for (int u = 0; u < 4; ++u) {
    gl2lds16(kb + (size_t)mbase * 256 + kOffL[u], sK + kLds[u]);
    gl2lds16(vb + (size_t)mbase * 2 + vOffL[u], sV + vLds[u]);
  }
  __syncthreads();

  for (int it = 0; it < iters; ++it) {
    const int m0 = mbase + it * 64;
    const int cur = it & 1, nxt = cur ^ 1;
    if (it + 1 < iters) {               // async-stage chunk it+1
      const int m1 = m0 + 64;
#pragma unroll
      for (int u = 0; u < 4; ++u) {
        gl2lds16(kb + (size_t)m1 * 256 + kOffL[u], sK + nxt * KB + kLds[u]);
        gl2lds16(vb + (size_t)m1 * 2 + vOffL[u], sV + nxt * VB + vLds[u]);
      }
    }

    // S^T = K Q^T: each K fragment feeds both q-groups
    floatx4 accST[2][4];
#pragma unroll
    for (int qg = 0; qg < 2; ++qg)
#pragma unroll
      for (int ng = 0; ng < 4; ++ng) accST[qg][ng] = (floatx4){0.f, 0.f, 0.f, 0.f};
#pragma unroll
    for (int ks = 0; ks < 4; ++ks)
#pragma unroll
      for (int ng = 0; ng < 4; ++ng) {
        bf16x8 kf = *(const bf16x8*)
            (sK + cur * KB + (ng * 16 + cidx) * 256 + ((ks * 4 + quad) ^ cidx) * 16);
        accST[0][ng] = __builtin_amdgcn_mfma_f32_16x16x32_bf16(kf, qf[0][ks], accST[0][ng], 0, 0, 0);
        accST[1][ng] = __builtin_amdgcn_mfma_f32_16x16x32_bf16(kf, qf[1][ks], accST[1][ng], 0, 0, 0);
      }

    // p = exp(s/sqrt(D)); denominator partials accumulate pre-mask
    float p[2][4][4];
#pragma unroll
    for (int qg = 0; qg < 2; ++qg)
#pragma unroll
      for (int ng = 0; ng < 4; ++ng)
#pragma unroll
        for (int r = 0; r < 4; ++r) {
          p[qg][ng][r] = exp2f(accST[qg][ng][r] * SC);
          lsum[qg] += p[qg][ng][r];
        }

    if (m0 + 63 > qmin) {               // else whole wave fully masked
#pragma unroll
      for (int qg = 0; qg < 2; ++qg) {
        const int base = qmin + qg * 16;
        if (m0 < base + 16) {           // straddle or fully-below: zero m<=n
#pragma unroll
          for (int ng = 0; ng < 4; ++ng)
#pragma unroll
            for (int r = 0; r < 4; ++r) {
              int m = m0 + ng * 16 + quad * 4 + r;
              int n = base + cidx;
              if (m <= n) p[qg][ng][r] = 0.f;
            }
        }
      }
      uint32_t pk[2][4][2];
#pragma unroll
      for (int qg = 0; qg < 2; ++qg)
#pragma unroll
        for (int ng = 0; ng < 4; ++ng) {
          pk[qg][ng][0] = pack2_bf16(p[qg][ng][0], p[qg][ng][1]);
          pk[qg][ng][1] = pack2_bf16(p[qg][ng][2], p[qg][ng][3]);
        }
      // PV: out^T += V^T P^T; V fragment read once, used for both q-groups
#pragma unroll
      for (int ks = 0; ks < 2; ++ks) {
        bf16x8 pbv[2];
#pragma unroll
        for (int qg = 0; qg < 2; ++qg) {
          u32x4 pbw;
#pragma unroll
          for (int j2 = 0; j2 < 4; ++j2) {
            int lr = ((quad & 1) << 3) + 2 * j2;
            int srcl = ((lr >> 2) << 4) + cidx;
            uint32_t lo = (uint32_t)__shfl((int)pk[qg][2 * ks][j2 & 1], srcl);
            uint32_t hi = (uint32_t)__shfl((int)pk[qg][2 * ks + 1][j2 & 1], srcl);
            pbw[j2] = (quad & 2) ? hi : lo;
          }
          pbv[qg] = __builtin_bit_cast(bf16x8, pbw);
        }
#pragma unroll
        for (int dg = 0; dg < 8; ++dg) {
          bf16x8 vf = *(const bf16x8*)
              (sV + cur * VB + (dg * 16 + cidx) * 128 +
               (((ks * 4 + quad) ^ cidx) & 7) * 16);
          O[0][dg] = __builtin_amdgcn_mfma_f32_16x16x32_bf16(vf, pbv[0], O[0][dg], 0, 0, 0);
          O[1][dg] = __builtin_amdgcn_mfma_f32_16x16x32_bf16(vf, pbv[1], O[1][dg], 0, 0, 0);
        }
      }
    }
    __syncthreads();   // drains it+1 async loads + guards buffer swap
  }

#pragma unroll
  for (int qg = 0; qg < 2; ++qg) {
    lsum[qg] += __shfl_xor(lsum[qg], 16);
    lsum[qg] += __shfl_xor(lsum[qg], 32);
    const int n = qmin + qg * 16 + cidx;
    float* op = opart + ((size_t)h * 16384 + b * 4096 + n) * 128;
#pragma unroll
    for (int dg = 0; dg < 8; ++dg)
      *(float4*)&op[dg * 16 + quad * 4] = __builtin_bit_cast(float4, O[qg][dg]);
    if (quad == 0) lpart[h * 16384 + b * 4096 + n] = lsum[qg];
  }
}

// ---------------- Phase 3: combine kv-chunks -------------------------------
__global__ __launch_bounds__(256) void combine_kernel(
    const float* __restrict__ opart, const float* __restrict__ lpart,
    float* __restrict__ out, int hcount) {
  size_t i = (size_t)blockIdx.x * 256 + threadIdx.x;
  size_t e = i * 4;
  int row = (int)(e >> 7);
  float4 acc = {0.f, 0.f, 0.f, 0.f};
  float l = 0.f;
  for (int h = 0; h < hcount; ++h) {
    float4 ov = *(const float4*)&opart[(size_t)h * 2097152 + e];
    acc.x += ov.x; acc.y += ov.y; acc.z += ov.z; acc.w += ov.w;
    l += lpart[h * 16384 + row];
  }
  float inv = 1.0f / l;
  float4 o;
  o.x = acc.x * inv; o.y = acc.y * inv; o.z = acc.z * inv; o.w = acc.w * inv;
  *(float4*)&out[e] = o;
}

extern "C" void kernel_launch(void* const* d_in, const int* in_sizes, int n_in,
                              void* d_out, int out_size, void* d_ws, size_t ws_size,
                              hipStream_t stream) {
  const float* x  = (const float*)d_in[0];
  const float* y  = (const float*)d_in[1];
  const float* Wq = (const float*)d_in[2];
  const float* Wk = (const float*)d_in[3];
  const float* Wv = (const float*)d_in[4];
  uint16_t* ws = (uint16_t*)d_ws;
  uint16_t* wt = ws;                      // 393216 u16
  uint16_t* q  = ws + 393216;             // 2097152 u16 (unscaled)
  uint16_t* k  = q + 2097152;
  uint16_t* vt = k + 2097152;             // [b][d][m]
  float* opart = (float*)((char*)d_ws + 13369344);
  int hcount = (ws_size >= (size_t)13369344 + 4 * 8454144) ? 4 : 2;
  float* lpart = opart + (size_t)hcount * 2097152;
  float* o = (float*)d_out;
  int mlen = 4096 / hcount, iters = mlen / 64;

  hipLaunchKernelGGL(wt_kernel,      dim3(192),            dim3(256), 0, stream, Wq, Wk, Wv, wt);
  hipLaunchKernelGGL(qkv_kernel,     dim3(128, 3),         dim3(512), 0, stream, x, y, wt, q, k, vt);
  hipLaunchKernelGGL(attn_kernel,    dim3(32, hcount, 4),  dim3(256), 0, stream, q, k, vt, opart, lpart, mlen, iters);
  hipLaunchKernelGGL(combine_kernel, dim3(2048),           dim3(256), 0, stream, opart, lpart, o, hcount);
}

// Round 3
// 230.917 us; speedup vs baseline: 1.0189x; 1.0189x over previous
//
#include <hip/hip_runtime.h>
#include <hip/hip_bf16.h>
#include <stdint.h>

// B=4, N=M=4096, C=1024, D=128. fp32 in/out, bf16 MFMA internally.
// out[n] = (sum_{m>n} e^{s[n,m]} v[m]) / (sum_all_m e^{s[n,m]})
// Fixed-frame softmax (s ~ N(0,1)) -> no running max; KV-split partials
// combine as plain (O, l) sums.
// Round 10: resubmit of the round-9 T3+T4 qkv pipeline (container failed;
// audit found no deadlock/fault path). Change vs round 9: main kt loop left
// rolled (no #pragma unroll) to cut code size / compile burden.
// qkv: raw s_barrier + counted s_waitcnt vmcnt(6) (never 0 in main loop) so
// next-ktile loads stay in flight across barriers; W staged via
// global_load_lds (bf16 direct), A staged fp32->reg->pack->ds_write; both
// LDS tiles g^=(row&7) 16B-granule XOR swizzled (stage-side + read-side).

typedef __attribute__((ext_vector_type(8))) __bf16    bf16x8;
typedef __attribute__((ext_vector_type(4))) float     floatx4;
typedef __attribute__((ext_vector_type(8))) uint16_t  u16x8;
typedef __attribute__((ext_vector_type(4))) uint32_t  u32x4;

#define DEVFN __device__ __forceinline__

DEVFN uint16_t f32_to_bf16(float f) {                 // round-to-nearest-even
  uint32_t u = __builtin_bit_cast(uint32_t, f);
  u += 0x7FFFu + ((u >> 16) & 1u);
  return (uint16_t)(u >> 16);
}

DEVFN uint32_t bcast(float f) { return __builtin_bit_cast(uint32_t, f); }

DEVFN uint32_t pack2_bf16(float a, float b) {         // round-half-up pair
  return ((bcast(a) + 0x8000u) >> 16) | ((bcast(b) + 0x8000u) & 0xFFFF0000u);
}

DEVFN u32x4 pack_bf16_8(float4 a0, float4 a1) {
  u32x4 o;
  o[0] = pack2_bf16(a0.x, a0.y);
  o[1] = pack2_bf16(a0.z, a0.w);
  o[2] = pack2_bf16(a1.x, a1.y);
  o[3] = pack2_bf16(a1.z, a1.w);
  return o;
}

DEVFN void gl2lds16(const void* g, void* l) {         // async 16B/lane -> LDS
  __builtin_amdgcn_global_load_lds(
      (const __attribute__((address_space(1))) void*)g,
      (__attribute__((address_space(3))) void*)l, 16, 0, 0);
}

// ---------------- Phase 0: W [1024,128] fp32 -> Wt [128,1024] bf16 (x3) ----
__global__ __launch_bounds__(256) void wt_kernel(
    const float* __restrict__ Wq, const float* __restrict__ Wk,
    const float* __restrict__ Wv, uint16_t* __restrict__ wt) {
  int tid = blockIdx.x * 256 + threadIdx.x;
  int mat = tid >> 14;
  int rem = tid & 16383;
  int n  = rem & 127;
  int k0 = rem >> 7;
  const float* W = (mat == 0) ? Wq : ((mat == 1) ? Wk : Wv);
  u16x8 v;
#pragma unroll
  for (int j = 0; j < 8; ++j) v[j] = f32_to_bf16(W[(k0 * 8 + j) * 128 + n]);
  *(u16x8*)&wt[mat * (128 * 1024) + n * 1024 + k0 * 8] = v;
}

// ---------------- Phase 1: fused QKV GEMM, counted-vmcnt pipeline ----------
// 128x128 tile, 16 ktiles of K=64. 512 thr = 8 waves (4 row x 2 col groups).
// LDS: A bf16 [128][64] + W bf16 [128][64], double-buffered = 64KB.
// Per iter: issue next W (2x gl2lds) + next A (4x dwordx4) -> vmcnt(6)
// -> pack/ds_write cur A -> lgkmcnt(0) -> s_barrier -> frags+MFMA ->
// lgkmcnt(0) -> s_barrier. Loads span the barriers (T4).
__global__ __launch_bounds__(512, 4) void qkv_kernel(
    const float* __restrict__ x, const float* __restrict__ y,
    const uint16_t* __restrict__ wt, uint16_t* __restrict__ q,
    uint16_t* __restrict__ k, uint16_t* __restrict__ vt) {
  constexpr int TB = 16384;               // one 128x64 bf16 tile, bytes
  __shared__ __align__(16) uint8_t sA[2 * TB];
  __shared__ __align__(16) uint8_t sW[2 * TB];
  const int t = threadIdx.x;
  const int mat = blockIdx.y, rt = blockIdx.x;
  const float* A = (mat == 0) ? x : y;
  const uint16_t* Wt = wt + mat * (128 * 1024);
  const int lane = t & 63, wv = t >> 6;   // wv 0..7
  const int wr = wv >> 1, wc = wv & 1;    // 4 row-groups x 2 col-groups
  const int cidx = lane & 15, quad = lane >> 4;
  const int Arow0 = rt * 128;

  // A staging: thread -> (row, 16-float chunk)
  const int ar  = t >> 2;                 // 0..127
  const int acq = t & 3;                  // chunk of 16 floats
  const float* aptr = &A[(size_t)(Arow0 + ar) * 1024 + acq * 16];
  const int aw0 = ar * 128 + (((2 * acq) ^ (ar & 7)) * 16);      // swz granule
  const int aw1 = ar * 128 + (((2 * acq + 1) ^ (ar & 7)) * 16);

  // W staging: 2 gl2lds issues; LDS linear granule G = i*512 + t
  int wsrc[2], wdst[2];
#pragma unroll
  for (int i = 0; i < 2; ++i) {
    int G = i * 512 + t;
    int n = G >> 3, g = G & 7;
    wsrc[i] = n * 1024 + ((g ^ (n & 7)) * 8);   // u16 offset (+ kt*64 later)
    wdst[i] = G * 16;                           // linear LDS bytes
  }

  floatx4 acc[2][4];
#pragma unroll
  for (int rg = 0; rg < 2; ++rg)
#pragma unroll
    for (int ng = 0; ng < 4; ++ng) acc[rg][ng] = (floatx4){0.f, 0.f, 0.f, 0.f};

  float4 f4[4], g4[4];

  // prologue: ktile 0 in flight
#pragma unroll
  for (int i = 0; i < 2; ++i)
    gl2lds16(Wt + wsrc[i], sW + wdst[i]);
#pragma unroll
  for (int j = 0; j < 4; ++j) f4[j] = *(const float4*)(aptr + j * 4);

  for (int kt = 0; kt < 16; ++kt) {
    const int cur = kt & 1, nxt = cur ^ 1;
    if (kt < 15) {                        // issue ktile kt+1 (stays in flight)
      const int kc = (kt + 1) * 64;
#pragma unroll
      for (int i = 0; i < 2; ++i)
        gl2lds16(Wt + kc + wsrc[i], sW + nxt * TB + wdst[i]);
#pragma unroll
      for (int j = 0; j < 4; ++j) g4[j] = *(const float4*)(aptr + kc + j * 4);
      __builtin_amdgcn_sched_barrier(0);
      asm volatile("s_waitcnt vmcnt(6)" ::: "memory");   // kt landed, kt+1 in flight
    } else {
      __builtin_amdgcn_sched_barrier(0);
      asm volatile("s_waitcnt vmcnt(0)" ::: "memory");
    }
    __builtin_amdgcn_sched_barrier(0);

    // pack current A chunk into LDS (swizzled)
    *(u32x4*)(sA + cur * TB + aw0) = pack_bf16_8(f4[0], f4[1]);
    *(u32x4*)(sA + cur * TB + aw1) = pack_bf16_8(f4[2], f4[3]);
    __builtin_amdgcn_sched_barrier(0);
    asm volatile("s_waitcnt lgkmcnt(0)" ::: "memory");   // ds_writes visible
    __builtin_amdgcn_s_barrier();
    __builtin_amdgcn_sched_barrier(0);

    bf16x8 af[2][2];
#pragma unroll
    for (int rg = 0; rg < 2; ++rg)
#pragma unroll
      for (int ks = 0; ks < 2; ++ks)
        af[rg][ks] = *(const bf16x8*)
            (sA + cur * TB + (wr * 32 + rg * 16 + cidx) * 128 +
             (((ks * 4 + quad) ^ (cidx & 7)) * 16));
#pragma unroll
    for (int ng = 0; ng < 4; ++ng) {
      const int n = wc * 64 + ng * 16 + cidx;
      bf16x8 b0 = *(const bf16x8*)
          (sW + cur * TB + n * 128 + (((quad) ^ (cidx & 7)) * 16));
      bf16x8 b1 = *(const bf16x8*)
          (sW + cur * TB + n * 128 + (((4 + quad) ^ (cidx & 7)) * 16));
#pragma unroll
      for (int rg = 0; rg < 2; ++rg) {
        acc[rg][ng] = __builtin_amdgcn_mfma_f32_16x16x32_bf16(af[rg][0], b0, acc[rg][ng], 0, 0, 0);
        acc[rg][ng] = __builtin_amdgcn_mfma_f32_16x16x32_bf16(af[rg][1], b1, acc[rg][ng], 0, 0, 0);
      }
    }
    __builtin_amdgcn_sched_barrier(0);
    asm volatile("s_waitcnt lgkmcnt(0)" ::: "memory");   // frag reads done
    __builtin_amdgcn_s_barrier();                        // buffer-swap guard
    __builtin_amdgcn_sched_barrier(0);

    if (kt < 15) {
#pragma unroll
      for (int j = 0; j < 4; ++j) f4[j] = g4[j];
    }
  }

  if (mat < 2) {
    uint16_t* outp = (mat == 0) ? q : k;
#pragma unroll
    for (int rg = 0; rg < 2; ++rg)
#pragma unroll
      for (int r = 0; r < 4; ++r) {
        int row = Arow0 + wr * 32 + rg * 16 + quad * 4 + r;
#pragma unroll
        for (int ng = 0; ng < 4; ++ng)
          outp[row * 128 + wc * 64 + ng * 16 + cidx] = f32_to_bf16(acc[rg][ng][r]);
      }
  } else {
    int bq = rt >> 5;
    int mbase = (rt & 31) * 128;
#pragma unroll
    for (int rg = 0; rg < 2; ++rg)
#pragma unroll
      for (int r = 0; r < 4; ++r) {
        int m = mbase + wr * 32 + rg * 16 + quad * 4 + r;
#pragma unroll
        for (int ng = 0; ng < 4; ++ng)
          vt[(size_t)(bq * 128 + wc * 64 + ng * 16 + cidx) * 4096 + m] =
              f32_to_bf16(acc[rg][ng][r]);
      }
  }
}

// ---------------- Phase 2: attention, 32 q-cols/wave, 2x fragment reuse ----
// grid (32 q-tiles, hcount kv-chunks, 4 batches), 256 thr = 4 waves x 32 q.
// K,V double-buffered unpadded LDS, XOR-swizzled via the global gather.
__global__ __launch_bounds__(256, 2) void attn_kernel(
    const uint16_t* __restrict__ q, const uint16_t* __restrict__ k,
    const uint16_t* __restrict__ vt, float* __restrict__ opart,
    float* __restrict__ lpart, int mlen, int iters) {
  constexpr int KB = 16384, VB = 16384;        // 64x128 / 128x64 u16, unpadded
  __shared__ __align__(16) uint8_t sK[2 * KB];
  __shared__ __align__(16) uint8_t sV[2 * VB];
  const int t = threadIdx.x;
  const int lane = t & 63, wv = t >> 6;
  const int cidx = lane & 15, quad = lane >> 4;
  const int qt = blockIdx.x, h = blockIdx.y, b = blockIdx.z;
  const int qmin = qt * 128 + wv * 32;         // lowest q row of this wave
  const int mbase = h * mlen;

  const uint16_t* qb = q + (size_t)(b * 4096) * 128;
  const uint8_t* kb = (const uint8_t*)(k + (size_t)(b * 4096) * 128);
  const uint8_t* vb = (const uint8_t*)(vt + (size_t)(b * 128) * 4096);

  const float SC = 0.12751744610657223f;  // log2(e)/sqrt(128), q unscaled

  // chunk-invariant swizzled gather offsets (see round-6 derivation)
  int kOffL[4], vOffL[4], kLds[4], vLds[4];
#pragma unroll
  for (int u = 0; u < 4; ++u) {
    int r  = wv * 16 + u * 4 + (lane >> 4);
    int g  = (lane & 15) ^ (r & 15);
    kOffL[u] = r * 256 + g * 16;
    kLds[u]  = (wv * 16 + u * 4) * 256;
    int rv = wv * 32 + u * 8 + (lane >> 3);
    int gv = (lane & 7) ^ (rv & 7);
    vOffL[u] = rv * 8192 + gv * 16;
    vLds[u]  = (wv * 32 + u * 8) * 128;
  }

  bf16x8 qf[2][4];   // B-frags: qg group col n = qmin+qg*16+cidx
#pragma unroll
  for (int qg = 0; qg < 2; ++qg)
#pragma unroll
    for (int ks = 0; ks < 4; ++ks)
      qf[qg][ks] = *(const bf16x8*)
          &qb[(qmin + qg * 16 + cidx) * 128 + ks * 32 + quad * 8];

  floatx4 O[2][8];   // out^T tiles: row d = dg*16+quad*4+r, col n per qg
#pragma unroll
  for (int qg = 0; qg < 2; ++qg)
#pragma unroll
    for (int dg = 0; dg < 8; ++dg) O[qg][dg] = (floatx4){0.f, 0.f, 0.f, 0.f};
  float lsum[2] = {0.f, 0.f};

  // stage chunk 0 into buffer 0
#pragma unroll
  for (int u = 0; u < 4; ++u) {
    gl2lds16(kb + (size_t)mbase * 256 + kOffL[u], sK + kLds[u]);
    gl2lds16(vb + (size_t)mbase * 2 + vOffL[u], sV + vLds[u]);
  }
  __syncthreads();

  for (int it = 0; it < iters; ++it) {
    const int m0 = mbase + it * 64;
    const int cur = it & 1, nxt = cur ^ 1;
    if (it + 1 < iters) {               // async-stage chunk it+1
      const int m1 = m0 + 64;
#pragma unroll
      for (int u = 0; u < 4; ++u) {
        gl2lds16(kb + (size_t)m1 * 256 + kOffL[u], sK + nxt * KB + kLds[u]);
        gl2lds16(vb + (size_t)m1 * 2 + vOffL[u], sV + nxt * VB + vLds[u]);
      }
    }

    // S^T = K Q^T: each K fragment feeds both q-groups
    floatx4 accST[2][4];
#pragma unroll
    for (int qg = 0; qg < 2; ++qg)
#pragma unroll
      for (int ng = 0; ng < 4; ++ng) accST[qg][ng] = (floatx4){0.f, 0.f, 0.f, 0.f};
#pragma unroll
    for (int ks = 0; ks < 4; ++ks)
#pragma unroll
      for (int ng = 0; ng < 4; ++ng) {
        bf16x8 kf = *(const bf16x8*)
            (sK + cur * KB + (ng * 16 + cidx) * 256 + ((ks * 4 + quad) ^ cidx) * 16);
        accST[0][ng] = __builtin_amdgcn_mfma_f32_16x16x32_bf16(kf, qf[0][ks], accST[0][ng], 0, 0, 0);
        accST[1][ng] = __builtin_amdgcn_mfma_f32_16x16x32_bf16(kf, qf[1][ks], accST[1][ng], 0, 0, 0);
      }

    // p = exp(s/sqrt(D)); denominator partials accumulate pre-mask
    float p[2][4][4];
#pragma unroll
    for (int qg = 0; qg < 2; ++qg)
#pragma unroll
      for (int ng = 0; ng < 4; ++ng)
#pragma unroll
        for (int r = 0; r < 4; ++r) {
          p[qg][ng][r] = exp2f(accST[qg][ng][r] * SC);
          lsum[qg] += p[qg][ng][r];
        }

    if (m0 + 63 > qmin) {               // else whole wave fully masked
#pragma unroll
      for (int qg = 0; qg < 2; ++qg) {
        const int base = qmin + qg * 16;
        if (m0 < base + 16) {           // straddle or fully-below: zero m<=n
#pragma unroll
          for (int ng = 0; ng < 4; ++ng)
#pragma unroll
            for (int r = 0; r < 4; ++r) {
              int m = m0 + ng * 16 + quad * 4 + r;
              int n = base + cidx;
              if (m <= n) p[qg][ng][r] = 0.f;
            }
        }
      }
      uint32_t pk[2][4][2];
#pragma unroll
      for (int qg = 0; qg < 2; ++qg)
#pragma unroll
        for (int ng = 0; ng < 4; ++ng) {
          pk[qg][ng][0] = pack2_bf16(p[qg][ng][0], p[qg][ng][1]);
          pk[qg][ng][1] = pack2_bf16(p[qg][ng][2], p[qg][ng][3]);
        }
      // PV: out^T += V^T P^T; V fragment read once, used for both q-groups
#pragma unroll
      for (int ks = 0; ks < 2; ++ks) {
        bf16x8 pbv[2];
#pragma unroll
        for (int qg = 0; qg < 2; ++qg) {
          u32x4 pbw;
#pragma unroll
          for (int j2 = 0; j2 < 4; ++j2) {
            int lr = ((quad & 1) << 3) + 2 * j2;
            int srcl = ((lr >> 2) << 4) + cidx;
            uint32_t lo = (uint32_t)__shfl((int)pk[qg][2 * ks][j2 & 1], srcl);
            uint32_t hi = (uint32_t)__shfl((int)pk[qg][2 * ks + 1][j2 & 1], srcl);
            pbw[j2] = (quad & 2) ? hi : lo;
          }
          pbv[qg] = __builtin_bit_cast(bf16x8, pbw);
        }
#pragma unroll
        for (int dg = 0; dg < 8; ++dg) {
          bf16x8 vf = *(const bf16x8*)
              (sV + cur * VB + (dg * 16 + cidx) * 128 +
               (((ks * 4 + quad) ^ cidx) & 7) * 16);
          O[0][dg] = __builtin_amdgcn_mfma_f32_16x16x32_bf16(vf, pbv[0], O[0][dg], 0, 0, 0);
          O[1][dg] = __builtin_amdgcn_mfma_f32_16x16x32_bf16(vf, pbv[1], O[1][dg], 0, 0, 0);
        }
      }
    }
    __syncthreads();   // drains it+1 async loads + guards buffer swap
  }

#pragma unroll
  for (int qg = 0; qg < 2; ++qg) {
    lsum[qg] += __shfl_xor(lsum[qg], 16);
    lsum[qg] += __shfl_xor(lsum[qg], 32);
    const int n = qmin + qg * 16 + cidx;
    float* op = opart + ((size_t)h * 16384 + b * 4096 + n) * 128;
#pragma unroll
    for (int dg = 0; dg < 8; ++dg)
      *(float4*)&op[dg * 16 + quad * 4] = __builtin_bit_cast(float4, O[qg][dg]);
    if (quad == 0) lpart[h * 16384 + b * 4096 + n] = lsum[qg];
  }
}

// ---------------- Phase 3: combine kv-chunks -------------------------------
__global__ __launch_bounds__(256) void combine_kernel(
    const float* __restrict__ opart, const float* __restrict__ lpart,
    float* __restrict__ out, int hcount) {
  size_t i = (size_t)blockIdx.x * 256 + threadIdx.x;
  size_t e = i * 4;
  int row = (int)(e >> 7);
  float4 acc = {0.f, 0.f, 0.f, 0.f};
  float l = 0.f;
  for (int h = 0; h < hcount; ++h) {
    float4 ov = *(const float4*)&opart[(size_t)h * 2097152 + e];
    acc.x += ov.x; acc.y += ov.y; acc.z += ov.z; acc.w += ov.w;
    l += lpart[h * 16384 + row];
  }
  float inv = 1.0f / l;
  float4 o;
  o.x = acc.x * inv; o.y = acc.y * inv; o.z = acc.z * inv; o.w = acc.w * inv;
  *(float4*)&out[e] = o;
}

extern "C" void kernel_launch(void* const* d_in, const int* in_sizes, int n_in,
                              void* d_out, int out_size, void* d_ws, size_t ws_size,
                              hipStream_t stream) {
  const float* x  = (const float*)d_in[0];
  const float* y  = (const float*)d_in[1];
  const float* Wq = (const float*)d_in[2];
  const float* Wk = (const float*)d_in[3];
  const float* Wv = (const float*)d_in[4];
  uint16_t* ws = (uint16_t*)d_ws;
  uint16_t* wt = ws;                      // 393216 u16
  uint16_t* q  = ws + 393216;             // 2097152 u16 (unscaled)
  uint16_t* k  = q + 2097152;
  uint16_t* vt = k + 2097152;             // [b][d][m]
  float* opart = (float*)((char*)d_ws + 13369344);
  int hcount = (ws_size >= (size_t)13369344 + 4 * 8454144) ? 4 : 2;
  float* lpart = opart + (size_t)hcount * 2097152;
  float* o = (float*)d_out;
  int mlen = 4096 / hcount, iters = mlen / 64;

  hipLaunchKernelGGL(wt_kernel,      dim3(192),            dim3(256), 0, stream, Wq, Wk, Wv, wt);
  hipLaunchKernelGGL(qkv_kernel,     dim3(128, 3),         dim3(512), 0, stream, x, y, wt, q, k, vt);
  hipLaunchKernelGGL(attn_kernel,    dim3(32, hcount, 4),  dim3(256), 0, stream, q, k, vt, opart, lpart, mlen, iters);
  hipLaunchKernelGGL(combine_kernel, dim3(2048),           dim3(256), 0, stream, opart, lpart, o, hcount);
}

// Round 4
// 230.116 us; speedup vs baseline: 1.0224x; 1.0035x over previous
//
#include <hip/hip_runtime.h>
#include <hip/hip_bf16.h>
#include <stdint.h>

// B=4, N=M=4096, C=1024, D=128. fp32 in/out, bf16 MFMA internally.
// out[n] = (sum_{m>n} e^{s[n,m]} v[m]) / (sum_all_m e^{s[n,m]})
// Fixed-frame softmax (s ~ N(0,1)) -> no running max; KV-split partials
// combine as plain (O, l) sums.
// Round 11: qkv re-tiled 128x128 -> 64x128 (768 blocks = exactly 3/CU,
// 48KB LDS -> 3 blocks/CU resident). Round-3 counted-vmcnt kept (vmcnt(8):
// 4 W-gl2lds + 4 A-loads per iter). Rationale: 384-block grid had 1.5
// blocks/CU avg -> half the CUs idle half the time; 3 balanced blocks/CU
// also give the scheduler independent waves to hide barrier phases.
// T5 s_setprio(1) around MFMA clusters in qkv + attn.

typedef __attribute__((ext_vector_type(8))) __bf16    bf16x8;
typedef __attribute__((ext_vector_type(4))) float     floatx4;
typedef __attribute__((ext_vector_type(8))) uint16_t  u16x8;
typedef __attribute__((ext_vector_type(4))) uint32_t  u32x4;

#define DEVFN __device__ __forceinline__

DEVFN uint16_t f32_to_bf16(float f) {                 // round-to-nearest-even
  uint32_t u = __builtin_bit_cast(uint32_t, f);
  u += 0x7FFFu + ((u >> 16) & 1u);
  return (uint16_t)(u >> 16);
}

DEVFN uint32_t bcast(float f) { return __builtin_bit_cast(uint32_t, f); }

DEVFN uint32_t pack2_bf16(float a, float b) {         // round-half-up pair
  return ((bcast(a) + 0x8000u) >> 16) | ((bcast(b) + 0x8000u) & 0xFFFF0000u);
}

DEVFN u32x4 pack_bf16_8(float4 a0, float4 a1) {
  u32x4 o;
  o[0] = pack2_bf16(a0.x, a0.y);
  o[1] = pack2_bf16(a0.z, a0.w);
  o[2] = pack2_bf16(a1.x, a1.y);
  o[3] = pack2_bf16(a1.z, a1.w);
  return o;
}

DEVFN void gl2lds16(const void* g, void* l) {         // async 16B/lane -> LDS
  __builtin_amdgcn_global_load_lds(
      (const __attribute__((address_space(1))) void*)g,
      (__attribute__((address_space(3))) void*)l, 16, 0, 0);
}

// ---------------- Phase 0: W [1024,128] fp32 -> Wt [128,1024] bf16 (x3) ----
__global__ __launch_bounds__(256) void wt_kernel(
    const float* __restrict__ Wq, const float* __restrict__ Wk,
    const float* __restrict__ Wv, uint16_t* __restrict__ wt) {
  int tid = blockIdx.x * 256 + threadIdx.x;
  int mat = tid >> 14;
  int rem = tid & 16383;
  int n  = rem & 127;
  int k0 = rem >> 7;
  const float* W = (mat == 0) ? Wq : ((mat == 1) ? Wk : Wv);
  u16x8 v;
#pragma unroll
  for (int j = 0; j < 8; ++j) v[j] = f32_to_bf16(W[(k0 * 8 + j) * 128 + n]);
  *(u16x8*)&wt[mat * (128 * 1024) + n * 1024 + k0 * 8] = v;
}

// ---------------- Phase 1: fused QKV GEMM, 64x128 tiles, 3 blocks/CU -------
// 768 blocks (256 row-tiles x 3 mats) = exactly 3/CU. 256 thr = 4 waves
// (2 row-groups x 2 col-groups; wave = 32 rows x 64 cols, acc[2][4]).
// LDS: A bf16 [64][64] (16KB dbuf) + W bf16 [128][64] (32KB dbuf) = 48KB.
// Per iter: issue next W (4x gl2lds) + next A (4x dwordx4) -> vmcnt(8)
// -> pack/ds_write cur A -> lgkmcnt(0) -> s_barrier -> frags + MFMA
// (setprio 1) -> lgkmcnt(0) -> s_barrier. Loads span barriers (T4).
__global__ __launch_bounds__(256, 3) void qkv_kernel(
    const float* __restrict__ x, const float* __restrict__ y,
    const uint16_t* __restrict__ wt, uint16_t* __restrict__ q,
    uint16_t* __restrict__ k, uint16_t* __restrict__ vt) {
  constexpr int AB = 8192;                // 64x64 bf16 tile, bytes
  constexpr int WB = 16384;               // 128x64 bf16 tile, bytes
  __shared__ __align__(16) uint8_t sA[2 * AB];
  __shared__ __align__(16) uint8_t sW[2 * WB];
  const int t = threadIdx.x;
  const int mat = blockIdx.y, rt = blockIdx.x;
  const float* A = (mat == 0) ? x : y;
  const uint16_t* Wt = wt + mat * (128 * 1024);
  const int lane = t & 63, wv = t >> 6;   // wv 0..3
  const int wr = wv >> 1, wc = wv & 1;    // 2 row-groups x 2 col-groups
  const int cidx = lane & 15, quad = lane >> 4;
  const int Arow0 = rt * 64;

  // A staging: thread -> (row 0..63, 16-float chunk)
  const int ar  = t >> 2;
  const int acq = t & 3;
  const float* aptr = &A[(size_t)(Arow0 + ar) * 1024 + acq * 16];
  const int aw0 = ar * 128 + (((2 * acq) ^ (ar & 7)) * 16);      // swz granule
  const int aw1 = ar * 128 + (((2 * acq + 1) ^ (ar & 7)) * 16);

  // W staging: 4 gl2lds issues; LDS linear granule G = i*256 + t
  int wsrc[4], wdst[4];
#pragma unroll
  for (int i = 0; i < 4; ++i) {
    int G = i * 256 + t;
    int n = G >> 3, g = G & 7;
    wsrc[i] = n * 1024 + ((g ^ (n & 7)) * 8);   // u16 offset (+ kt*64 later)
    wdst[i] = G * 16;                           // linear LDS bytes
  }

  floatx4 acc[2][4];
#pragma unroll
  for (int rg = 0; rg < 2; ++rg)
#pragma unroll
    for (int ng = 0; ng < 4; ++ng) acc[rg][ng] = (floatx4){0.f, 0.f, 0.f, 0.f};

  float4 f4[4], g4[4];

  // prologue: ktile 0 in flight
#pragma unroll
  for (int i = 0; i < 4; ++i)
    gl2lds16(Wt + wsrc[i], sW + wdst[i]);
#pragma unroll
  for (int j = 0; j < 4; ++j) f4[j] = *(const float4*)(aptr + j * 4);

  for (int kt = 0; kt < 16; ++kt) {
    const int cur = kt & 1, nxt = cur ^ 1;
    if (kt < 15) {                        // issue ktile kt+1 (stays in flight)
      const int kc = (kt + 1) * 64;
#pragma unroll
      for (int i = 0; i < 4; ++i)
        gl2lds16(Wt + kc + wsrc[i], sW + nxt * WB + wdst[i]);
#pragma unroll
      for (int j = 0; j < 4; ++j) g4[j] = *(const float4*)(aptr + kc + j * 4);
      __builtin_amdgcn_sched_barrier(0);
      asm volatile("s_waitcnt vmcnt(8)" ::: "memory");   // kt landed, kt+1 in flight
    } else {
      __builtin_amdgcn_sched_barrier(0);
      asm volatile("s_waitcnt vmcnt(0)" ::: "memory");
    }
    __builtin_amdgcn_sched_barrier(0);

    // pack current A chunk into LDS (swizzled)
    *(u32x4*)(sA + cur * AB + aw0) = pack_bf16_8(f4[0], f4[1]);
    *(u32x4*)(sA + cur * AB + aw1) = pack_bf16_8(f4[2], f4[3]);
    __builtin_amdgcn_sched_barrier(0);
    asm volatile("s_waitcnt lgkmcnt(0)" ::: "memory");   // ds_writes visible
    __builtin_amdgcn_s_barrier();
    __builtin_amdgcn_sched_barrier(0);

    bf16x8 af[2][2];
#pragma unroll
    for (int rg = 0; rg < 2; ++rg)
#pragma unroll
      for (int ks = 0; ks < 2; ++ks)
        af[rg][ks] = *(const bf16x8*)
            (sA + cur * AB + (wr * 32 + rg * 16 + cidx) * 128 +
             (((ks * 4 + quad) ^ (cidx & 7)) * 16));
    __builtin_amdgcn_s_setprio(1);
#pragma unroll
    for (int ng = 0; ng < 4; ++ng) {
      const int n = wc * 64 + ng * 16 + cidx;
      bf16x8 b0 = *(const bf16x8*)
          (sW + cur * WB + n * 128 + (((quad) ^ (cidx & 7)) * 16));
      bf16x8 b1 = *(const bf16x8*)
          (sW + cur * WB + n * 128 + (((4 + quad) ^ (cidx & 7)) * 16));
#pragma unroll
      for (int rg = 0; rg < 2; ++rg) {
        acc[rg][ng] = __builtin_amdgcn_mfma_f32_16x16x32_bf16(af[rg][0], b0, acc[rg][ng], 0, 0, 0);
        acc[rg][ng] = __builtin_amdgcn_mfma_f32_16x16x32_bf16(af[rg][1], b1, acc[rg][ng], 0, 0, 0);
      }
    }
    __builtin_amdgcn_s_setprio(0);
    __builtin_amdgcn_sched_barrier(0);
    asm volatile("s_waitcnt lgkmcnt(0)" ::: "memory");   // frag reads done
    __builtin_amdgcn_s_barrier();                        // buffer-swap guard
    __builtin_amdgcn_sched_barrier(0);

    if (kt < 15) {
#pragma unroll
      for (int j = 0; j < 4; ++j) f4[j] = g4[j];
    }
  }

  if (mat < 2) {
    uint16_t* outp = (mat == 0) ? q : k;
#pragma unroll
    for (int rg = 0; rg < 2; ++rg)
#pragma unroll
      for (int r = 0; r < 4; ++r) {
        int row = Arow0 + wr * 32 + rg * 16 + quad * 4 + r;
#pragma unroll
        for (int ng = 0; ng < 4; ++ng)
          outp[row * 128 + wc * 64 + ng * 16 + cidx] = f32_to_bf16(acc[rg][ng][r]);
      }
  } else {
    int bq = rt >> 6;
    int mbase = (rt & 63) * 64;
#pragma unroll
    for (int rg = 0; rg < 2; ++rg)
#pragma unroll
      for (int r = 0; r < 4; ++r) {
        int m = mbase + wr * 32 + rg * 16 + quad * 4 + r;
#pragma unroll
        for (int ng = 0; ng < 4; ++ng)
          vt[(size_t)(bq * 128 + wc * 64 + ng * 16 + cidx) * 4096 + m] =
              f32_to_bf16(acc[rg][ng][r]);
      }
  }
}

// ---------------- Phase 2: attention, 32 q-cols/wave, 2x fragment reuse ----
// grid (32 q-tiles, hcount kv-chunks, 4 batches), 256 thr = 4 waves x 32 q.
// K,V double-buffered unpadded LDS, XOR-swizzled via the global gather.
__global__ __launch_bounds__(256, 2) void attn_kernel(
    const uint16_t* __restrict__ q, const uint16_t* __restrict__ k,
    const uint16_t* __restrict__ vt, float* __restrict__ opart,
    float* __restrict__ lpart, int mlen, int iters) {
  constexpr int KB = 16384, VB = 16384;        // 64x128 / 128x64 u16, unpadded
  __shared__ __align__(16) uint8_t sK[2 * KB];
  __shared__ __align__(16) uint8_t sV[2 * VB];
  const int t = threadIdx.x;
  const int lane = t & 63, wv = t >> 6;
  const int cidx = lane & 15, quad = lane >> 4;
  const int qt = blockIdx.x, h = blockIdx.y, b = blockIdx.z;
  const int qmin = qt * 128 + wv * 32;         // lowest q row of this wave
  const int mbase = h * mlen;

  const uint16_t* qb = q + (size_t)(b * 4096) * 128;
  const uint8_t* kb = (const uint8_t*)(k + (size_t)(b * 4096) * 128);
  const uint8_t* vb = (const uint8_t*)(vt + (size_t)(b * 128) * 4096);

  const float SC = 0.12751744610657223f;  // log2(e)/sqrt(128), q unscaled

  // chunk-invariant swizzled gather offsets (see round-6 derivation)
  int kOffL[4], vOffL[4], kLds[4], vLds[4];
#pragma unroll
  for (int u = 0; u < 4; ++u) {
    int r  = wv * 16 + u * 4 + (lane >> 4);
    int g  = (lane & 15) ^ (r & 15);
    kOffL[u] = r * 256 + g * 16;
    kLds[u]  = (wv * 16 + u * 4) * 256;
    int rv = wv * 32 + u * 8 + (lane >> 3);
    int gv = (lane & 7) ^ (rv & 7);
    vOffL[u] = rv * 8192 + gv * 16;
    vLds[u]  = (wv * 32 + u * 8) * 128;
  }

  bf16x8 qf[2][4];   // B-frags: qg group col n = qmin+qg*16+cidx
#pragma unroll
  for (int qg = 0; qg < 2; ++qg)
#pragma unroll
    for (int ks = 0; ks < 4; ++ks)
      qf[qg][ks] = *(const bf16x8*)
          &qb[(qmin + qg * 16 + cidx) * 128 + ks * 32 + quad * 8];

  floatx4 O[2][8];   // out^T tiles: row d = dg*16+quad*4+r, col n per qg
#pragma unroll
  for (int qg = 0; qg < 2; ++qg)
#pragma unroll
    for (int dg = 0; dg < 8; ++dg) O[qg][dg] = (floatx4){0.f, 0.f, 0.f, 0.f};
  float lsum[2] = {0.f, 0.f};

  // stage chunk 0 into buffer 0
#pragma unroll
  for (int u = 0; u < 4; ++u) {
    gl2lds16(kb + (size_t)mbase * 256 + kOffL[u], sK + kLds[u]);
    gl2lds16(vb + (size_t)mbase * 2 + vOffL[u], sV + vLds[u]);
  }
  __syncthreads();

  for (int it = 0; it < iters; ++it) {
    const int m0 = mbase + it * 64;
    const int cur = it & 1, nxt = cur ^ 1;
    if (it + 1 < iters) {               // async-stage chunk it+1
      const int m1 = m0 + 64;
#pragma unroll
      for (int u = 0; u < 4; ++u) {
        gl2lds16(kb + (size_t)m1 * 256 + kOffL[u], sK + nxt * KB + kLds[u]);
        gl2lds16(vb + (size_t)m1 * 2 + vOffL[u], sV + nxt * VB + vLds[u]);
      }
    }

    // S^T = K Q^T: each K fragment feeds both q-groups
    floatx4 accST[2][4];
#pragma unroll
    for (int qg = 0; qg < 2; ++qg)
#pragma unroll
      for (int ng = 0; ng < 4; ++ng) accST[qg][ng] = (floatx4){0.f, 0.f, 0.f, 0.f};
    __builtin_amdgcn_s_setprio(1);
#pragma unroll
    for (int ks = 0; ks < 4; ++ks)
#pragma unroll
      for (int ng = 0; ng < 4; ++ng) {
        bf16x8 kf = *(const bf16x8*)
            (sK + cur * KB + (ng * 16 + cidx) * 256 + ((ks * 4 + quad) ^ cidx) * 16);
        accST[0][ng] = __builtin_amdgcn_mfma_f32_16x16x32_bf16(kf, qf[0][ks], accST[0][ng], 0, 0, 0);
        accST[1][ng] = __builtin_amdgcn_mfma_f32_16x16x32_bf16(kf, qf[1][ks], accST[1][ng], 0, 0, 0);
      }
    __builtin_amdgcn_s_setprio(0);

    // p = exp(s/sqrt(D)); denominator partials accumulate pre-mask
    float p[2][4][4];
#pragma unroll
    for (int qg = 0; qg < 2; ++qg)
#pragma unroll
      for (int ng = 0; ng < 4; ++ng)
#pragma unroll
        for (int r = 0; r < 4; ++r) {
          p[qg][ng][r] = exp2f(accST[qg][ng][r] * SC);
          lsum[qg] += p[qg][ng][r];
        }

    if (m0 + 63 > qmin) {               // else whole wave fully masked
#pragma unroll
      for (int qg = 0; qg < 2; ++qg) {
        const int base = qmin + qg * 16;
        if (m0 < base + 16) {           // straddle or fully-below: zero m<=n
#pragma unroll
          for (int ng = 0; ng < 4; ++ng)
#pragma unroll
            for (int r = 0; r < 4; ++r) {
              int m = m0 + ng * 16 + quad * 4 + r;
              int n = base + cidx;
              if (m <= n) p[qg][ng][r] = 0.f;
            }
        }
      }
      uint32_t pk[2][4][2];
#pragma unroll
      for (int qg = 0; qg < 2; ++qg)
#pragma unroll
        for (int ng = 0; ng < 4; ++ng) {
          pk[qg][ng][0] = pack2_bf16(p[qg][ng][0], p[qg][ng][1]);
          pk[qg][ng][1] = pack2_bf16(p[qg][ng][2], p[qg][ng][3]);
        }
      // PV: out^T += V^T P^T; V fragment read once, used for both q-groups
#pragma unroll
      for (int ks = 0; ks < 2; ++ks) {
        bf16x8 pbv[2];
#pragma unroll
        for (int qg = 0; qg < 2; ++qg) {
          u32x4 pbw;
#pragma unroll
          for (int j2 = 0; j2 < 4; ++j2) {
            int lr = ((quad & 1) << 3) + 2 * j2;
            int srcl = ((lr >> 2) << 4) + cidx;
            uint32_t lo = (uint32_t)__shfl((int)pk[qg][2 * ks][j2 & 1], srcl);
            uint32_t hi = (uint32_t)__shfl((int)pk[qg][2 * ks + 1][j2 & 1], srcl);
            pbw[j2] = (quad & 2) ? hi : lo;
          }
          pbv[qg] = __builtin_bit_cast(bf16x8, pbw);
        }
        __builtin_amdgcn_s_setprio(1);
#pragma unroll
        for (int dg = 0; dg < 8; ++dg) {
          bf16x8 vf = *(const bf16x8*)
              (sV + cur * VB + (dg * 16 + cidx) * 128 +
               (((ks * 4 + quad) ^ cidx) & 7) * 16);
          O[0][dg] = __builtin_amdgcn_mfma_f32_16x16x32_bf16(vf, pbv[0], O[0][dg], 0, 0, 0);
          O[1][dg] = __builtin_amdgcn_mfma_f32_16x16x32_bf16(vf, pbv[1], O[1][dg], 0, 0, 0);
        }
        __builtin_amdgcn_s_setprio(0);
      }
    }
    __syncthreads();   // drains it+1 async loads + guards buffer swap
  }

#pragma unroll
  for (int qg = 0; qg < 2; ++qg) {
    lsum[qg] += __shfl_xor(lsum[qg], 16);
    lsum[qg] += __shfl_xor(lsum[qg], 32);
    const int n = qmin + qg * 16 + cidx;
    float* op = opart + ((size_t)h * 16384 + b * 4096 + n) * 128;
#pragma unroll
    for (int dg = 0; dg < 8; ++dg)
      *(float4*)&op[dg * 16 + quad * 4] = __builtin_bit_cast(float4, O[qg][dg]);
    if (quad == 0) lpart[h * 16384 + b * 4096 + n] = lsum[qg];
  }
}

// ---------------- Phase 3: combine kv-chunks -------------------------------
__global__ __launch_bounds__(256) void combine_kernel(
    const float* __restrict__ opart, const float* __restrict__ lpart,
    float* __restrict__ out, int hcount) {
  size_t i = (size_t)blockIdx.x * 256 + threadIdx.x;
  size_t e = i * 4;
  int row = (int)(e >> 7);
  float4 acc = {0.f, 0.f, 0.f, 0.f};
  float l = 0.f;
  for (int h = 0; h < hcount; ++h) {
    float4 ov = *(const float4*)&opart[(size_t)h * 2097152 + e];
    acc.x += ov.x; acc.y += ov.y; acc.z += ov.z; acc.w += ov.w;
    l += lpart[h * 16384 + row];
  }
  float inv = 1.0f / l;
  float4 o;
  o.x = acc.x * inv; o.y = acc.y * inv; o.z = acc.z * inv; o.w = acc.w * inv;
  *(float4*)&out[e] = o;
}

extern "C" void kernel_launch(void* const* d_in, const int* in_sizes, int n_in,
                              void* d_out, int out_size, void* d_ws, size_t ws_size,
                              hipStream_t stream) {
  const float* x  = (const float*)d_in[0];
  const float* y  = (const float*)d_in[1];
  const float* Wq = (const float*)d_in[2];
  const float* Wk = (const float*)d_in[3];
  const float* Wv = (const float*)d_in[4];
  uint16_t* ws = (uint16_t*)d_ws;
  uint16_t* wt = ws;                      // 393216 u16
  uint16_t* q  = ws + 393216;             // 2097152 u16 (unscaled)
  uint16_t* k  = q + 2097152;
  uint16_t* vt = k + 2097152;             // [b][d][m]
  float* opart = (float*)((char*)d_ws + 13369344);
  int hcount = (ws_size >= (size_t)13369344 + 4 * 8454144) ? 4 : 2;
  float* lpart = opart + (size_t)hcount * 2097152;
  float* o = (float*)d_out;
  int mlen = 4096 / hcount, iters = mlen / 64;

  hipLaunchKernelGGL(wt_kernel,      dim3(192),            dim3(256), 0, stream, Wq, Wk, Wv, wt);
  hipLaunchKernelGGL(qkv_kernel,     dim3(256, 3),         dim3(256), 0, stream, x, y, wt, q, k, vt);
  hipLaunchKernelGGL(attn_kernel,    dim3(32, hcount, 4),  dim3(256), 0, stream, q, k, vt, opart, lpart, mlen, iters);
  hipLaunchKernelGGL(combine_kernel, dim3(2048),           dim3(256), 0, stream, opart, lpart, o, hcount);
}